// Round 13
// baseline (299.305 us; speedup 1.0000x reference)
//
#include <hip/hip_runtime.h>
#include <stdint.h>

#define TSIZE   (1u<<19)
#define P2c 2654435761u
#define P3c 805459861u

#define NTHR 512          // fused fallback block
#define BM 256

// LDS layout (bytes) — fused fallback
#define H_OFF   0u
#define W1_OFF  65536u
#define W2_OFF  73728u
#define W3_OFF  106496u
#define W4_OFF  139264u
#define B_OFF   143360u
#define LDS_BYTES 144960u

// LDS layout (bytes) — mlp kernel (weights only, swizzled; VERIFIED R6-R12)
#define MW1   0u          // 128 rows x 64B   (8 KB)
#define MW2   8192u       // 128 rows x 256B  (32 KB)
#define MW3   40960u      // 128 rows x 256B  (32 KB)
#define MW4   73728u      // 16 rows x 256B   (4 KB)
#define MBIAS 77824u      // f32: b1[128] b2[128] b3[128] b4[2]
#define MLP_LDS_BYTES 79872u
#define WIMG_BYTES 81920u  // image padded to 16B multiple

typedef _Float16 v8h __attribute__((ext_vector_type(8)));
typedef _Float16 v4h __attribute__((ext_vector_type(4)));
typedef float    v4f __attribute__((ext_vector_type(4)));

__device__ __forceinline__ uint32_t swz256(uint32_t row, uint32_t off){ return row*256u + (off ^ ((row&7u)<<4)); }
__device__ __forceinline__ uint32_t swz64 (uint32_t row, uint32_t off){ return row*64u  + (off ^ ((row&3u)<<4)); }

__device__ __forceinline__ uint32_t pkh(float a, float b){
  union { _Float16 h[2]; uint32_t u; } t;
  t.h[0] = (_Float16)a; t.h[1] = (_Float16)b; return t.u;
}
__device__ __forceinline__ v8h mk8(const uint32_t* w){
  union { uint32_t u[4]; v8h h; } t;
  t.u[0]=w[0]; t.u[1]=w[1]; t.u[2]=w[2]; t.u[3]=w[3]; return t.h;
}
__device__ __forceinline__ v4h mk4(uint32_t a, uint32_t b){
  union { uint32_t u[2]; v4h h; } t;
  t.u[0]=a; t.u[1]=b; return t.h;
}

__device__ __forceinline__ void sh16(float dx, float dy, float dz, float* s){
  float x2=dx*dx, y2=dy*dy, z2=dz*dz;
  float xy=dx*dy, yz=dy*dz, xz=dx*dz;
  s[0]=0.28209479177387814f;
  s[1]=-0.48860251190291987f*dy;
  s[2]= 0.48860251190291987f*dz;
  s[3]=-0.48860251190291987f*dx;
  s[4]= 1.0925484305920792f*xy;
  s[5]=-1.0925484305920792f*yz;
  s[6]= 0.94617469575756f*z2-0.31539156525252f;
  s[7]=-1.0925484305920792f*xz;
  s[8]= 0.5462742152960396f*(x2-y2);
  s[9]= 0.5900435899266435f*dy*(-3.f*x2+y2);
  s[10]=2.890611442640554f*xy*dz;
  s[11]=0.4570457994644657f*dy*(1.f-5.f*z2);
  s[12]=0.3731763325901154f*dz*(5.f*z2-3.f);
  s[13]=0.4570457994644657f*dx*(1.f-5.f*z2);
  s[14]=1.445305721320277f*dz*(x2-y2);
  s[15]=0.5900435899266435f*dx*(-x2+3.f*y2);
}

// ============================ kernel 0: combined prep (table+wimg+xyz; R12-verified) ==
__global__ __launch_bounds__(256)
void prep_all(const float* __restrict__ t, _Float16* __restrict__ o, int n4,
              const float* __restrict__ x, float4* __restrict__ xyz, int N,
              const float* __restrict__ W1, const float* __restrict__ W2,
              const float* __restrict__ W3, const float* __restrict__ W4,
              const float* __restrict__ b1, const float* __restrict__ b2,
              const float* __restrict__ b3, const float* __restrict__ b4,
              char* __restrict__ img)
{
  int gid = (int)(blockIdx.x*256 + threadIdx.x);
  int stride = (int)(gridDim.x*256);
  for (int i = gid; i < n4; i += stride){
    float4 v = ((const float4*)t)[i];
    v4h h; h[0]=(_Float16)v.x; h[1]=(_Float16)v.y; h[2]=(_Float16)v.z; h[3]=(_Float16)v.w;
    ((v4h*)o)[i] = h;
    if (xyz && i < N){
      float4 p; p.x = x[i*6+0]; p.y = x[i*6+1]; p.z = x[i*6+2]; p.w = 0.f;
      xyz[i] = p;
    }
    if (i < 128*128){
      int row = i >> 7, k = i & 127;
      uint32_t byte = (uint32_t)(k*2) ^ (uint32_t)((row&15)<<3);
      *(_Float16*)(img + MW2 + (uint32_t)row*256u + byte) = (_Float16)W2[i];
      *(_Float16*)(img + MW3 + (uint32_t)row*256u + byte) = (_Float16)W3[i];
    }
    if (i < 128*32){
      int row = i >> 5, k = i & 31;
      uint32_t byte = (uint32_t)(k*2) ^ (uint32_t)((row&3)<<4);
      *(_Float16*)(img + MW1 + (uint32_t)row*64u + byte) = (_Float16)W1[i];
    }
    if (i < 16*128){
      int row = i >> 7, k = i & 127;
      uint32_t byte = (uint32_t)(k*2) ^ (uint32_t)((row&15)<<3);
      _Float16 v2 = (i < 256) ? (_Float16)W4[i] : (_Float16)0.f;
      *(_Float16*)(img + MW4 + (uint32_t)row*256u + byte) = v2;
    }
    if (i < 128){
      float* bl = (float*)(img + MBIAS);
      bl[i] = b1[i]; bl[128+i] = b2[i]; bl[256+i] = b3[i];
      if (i < 2) bl[384+i] = b4[i];
    }
  }
}

// ============================ encode compute (weights+interp from loaded corners) =====
__device__ __forceinline__ uint32_t enc_fin(float px, float py, float pz,
                                            uint32_t u0, uint32_t u1, uint32_t u2, uint32_t u3,
                                            uint32_t u4, uint32_t u5, uint32_t u6, uint32_t u7)
{
  float rx = px-floorf(px), ry = py-floorf(py), rz = pz-floorf(pz);
  float wx0=1.f-rx, wy0=1.f-ry, wz0=1.f-rz;
  float w0=wx0*wy0*wz0, w1=rx*wy0*wz0, w2=wx0*ry*wz0, w3=rx*ry*wz0;
  float w4=wx0*wy0*rz,  w5=rx*wy0*rz,  w6=wx0*ry*rz,  w7=rx*ry*rz;
  union { uint32_t u; _Float16 h[2]; } c0,c1,c2,c3,c4,c5,c6,c7;
  c0.u=u0; c1.u=u1; c2.u=u2; c3.u=u3; c4.u=u4; c5.u=u5; c6.u=u6; c7.u=u7;
  float s0 = (float)c0.h[0]*w0+(float)c1.h[0]*w1+(float)c2.h[0]*w2+(float)c3.h[0]*w3
           + (float)c4.h[0]*w4+(float)c5.h[0]*w5+(float)c6.h[0]*w6+(float)c7.h[0]*w7;
  float s1 = (float)c0.h[1]*w0+(float)c1.h[1]*w1+(float)c2.h[1]*w2+(float)c3.h[1]*w3
           + (float)c4.h[1]*w4+(float)c5.h[1]*w5+(float)c6.h[1]*w6+(float)c7.h[1]*w7;
  return pkh(s0, s1);
}

// ============================ kernel 1a: encode, 512-thread blocks ====================
// 512 thr x 8 waves -> 4 blocks/CU = 32 waves resident (was ~17 at 54% occupancy).
__global__ __launch_bounds__(512)
void encode4(const float4* __restrict__ xyz, const _Float16* __restrict__ tb,
             uint32_t* __restrict__ planes, int N)
{
  const int lev = (int)(blockIdx.x & 7u);
  const int nch = (N + 1023) >> 10;                // chunks of 1024 rows
  const uint32_t* lvl = (const uint32_t*)(tb + (size_t)lev*TSIZE*2u);
  const float res = (float)(16 << lev);
  const uint32_t m = TSIZE-1u;
  uint32_t* plane = planes + (size_t)lev*(size_t)N;
  for (int c = (int)(blockIdx.x >> 3); c < nch; c += (int)(gridDim.x >> 3)){
    int row0 = c*1024 + (int)threadIdx.x;
    #pragma unroll
    for (int h=0; h<2; h++){
      int row = row0 + h*512;
      if (row < N){
        float4 p = xyz[row];
        float px = p.x*res, py = p.y*res, pz = p.z*res;
        uint32_t ix=(uint32_t)floorf(px), iy=(uint32_t)floorf(py), iz=(uint32_t)floorf(pz);
        uint32_t hx0=ix,      hx1=ix+1u;
        uint32_t hy0=iy*P2c,  hy1=(iy+1u)*P2c;
        uint32_t hz0=iz*P3c,  hz1=(iz+1u)*P3c;
        plane[row] = enc_fin(px, py, pz,
                             lvl[(hx0^hy0^hz0)&m], lvl[(hx1^hy0^hz0)&m],
                             lvl[(hx0^hy1^hz0)&m], lvl[(hx1^hy1^hz0)&m],
                             lvl[(hx0^hy0^hz1)&m], lvl[(hx1^hy0^hz1)&m],
                             lvl[(hx0^hy1^hz1)&m], lvl[(hx1^hy1^hz1)&m]);
      }
    }
  }
}

// ============================ kernel 1b: encode from raw x (mid tier; R10-verified) ===
__global__ __launch_bounds__(256)
void encode(const float* __restrict__ x, const _Float16* __restrict__ tb,
            uint32_t* __restrict__ planes, int N)
{
  const int lev = (int)(blockIdx.x & 7u);
  const int nch = (N + 511) >> 9;
  const uint32_t* lvl = (const uint32_t*)(tb + (size_t)lev*TSIZE*2u);
  const float res = (float)(16 << lev);
  const uint32_t m = TSIZE-1u;
  uint32_t* plane = planes + (size_t)lev*(size_t)N;
  for (int c = (int)(blockIdx.x >> 3); c < nch; c += (int)(gridDim.x >> 3)){
    int row0 = c*512 + (int)threadIdx.x;
    #pragma unroll
    for (int h=0; h<2; h++){
      int row = row0 + h*256;
      if (row < N){
        float px = x[row*6+0]*res, py = x[row*6+1]*res, pz = x[row*6+2]*res;
        uint32_t ix=(uint32_t)floorf(px), iy=(uint32_t)floorf(py), iz=(uint32_t)floorf(pz);
        uint32_t hx0=ix,      hx1=ix+1u;
        uint32_t hy0=iy*P2c,  hy1=(iy+1u)*P2c;
        uint32_t hz0=iz*P3c,  hz1=(iz+1u)*P3c;
        plane[row] = enc_fin(px, py, pz,
                             lvl[(hx0^hy0^hz0)&m], lvl[(hx1^hy0^hz0)&m],
                             lvl[(hx0^hy1^hz0)&m], lvl[(hx1^hy1^hz0)&m],
                             lvl[(hx0^hy0^hz1)&m], lvl[(hx1^hy0^hz1)&m],
                             lvl[(hx0^hy1^hz1)&m], lvl[(hx1^hy1^hz1)&m]);
      }
    }
  }
}

// ============================ kernel 2: MLP — RT=4, 512 rows/block, one-shot ==========
// Identity-repack structure (RT=4 math HW-verified in R5's mlp_reg, VGPR 216 no spill).
// 8 waves x 64 rows = 512 rows/block -> half the blocks of R11 -> half the total
// 78KB-staging work. One-shot (no persistent loop -> no LICM address spill, R10 lesson).
__global__ __launch_bounds__(512, 1)
void mlp_oneshot4(const float* __restrict__ x, const uint32_t* __restrict__ planes,
                  const float4* __restrict__ wimg,
                  float* __restrict__ out, int N)
{
  extern __shared__ char sm[];
  const int tid  = (int)threadIdx.x;
  const int lane = tid & 63;
  const int wave = tid >> 6;      // 0..7
  const int r = lane & 15;
  const int q = lane >> 4;

  // ---- stage weight image: linear, coalesced, conflict-free ----
  {
    float4* l = (float4*)sm;
    for (int j = tid; j < (int)(MLP_LDS_BYTES/16); j += 512) l[j] = wimg[j];
  }
  __syncthreads();
  const float* bl = (const float*)(sm + MBIAS);

  const int R0 = (int)blockIdx.x*512 + wave*64;

  // ---- layer-1 B-frags from encoded features (K=32, k-chunk = q*8..q*8+7) ----
  uint32_t b1w[4][4];
  #pragma unroll
  for (int rt=0; rt<4; rt++){
    int R  = R0 + rt*16 + r;
    int Rc = (R < N) ? R : 0;
    if (q < 2){
      #pragma unroll
      for (int i=0; i<4; i++)
        b1w[rt][i] = planes[(size_t)(q*4+i)*(size_t)N + (size_t)Rc];
    } else {
      float dx = 2.f*x[Rc*6+3]-1.f, dy = 2.f*x[Rc*6+4]-1.f, dz = 2.f*x[Rc*6+5]-1.f;
      float s[16]; sh16(dx, dy, dz, s);
      if (q == 2){
        b1w[rt][0]=pkh(s[0],s[1]);  b1w[rt][1]=pkh(s[2],s[3]);
        b1w[rt][2]=pkh(s[4],s[5]);  b1w[rt][3]=pkh(s[6],s[7]);
      } else {
        b1w[rt][0]=pkh(s[8],s[9]);   b1w[rt][1]=pkh(s[10],s[11]);
        b1w[rt][2]=pkh(s[12],s[13]); b1w[rt][3]=pkh(s[14],s[15]);
      }
    }
  }

  v4f acc[4][8];
  #pragma unroll
  for (int rt=0; rt<4; rt++)
    #pragma unroll
    for (int ct=0; ct<8; ct++){ v4f z={0.f,0.f,0.f,0.f}; acc[rt][ct]=z; }

  // ---- layer 1 (K=32 MFMA, A from LDS w1; R6-verified address) ----
  #pragma unroll
  for (int ct=0; ct<8; ct++){
    v8h a = *(const v8h*)(sm + MW1 + (uint32_t)(ct*16+r)*64u
                          + (uint32_t)((q*16) ^ ((r&3)<<4)));
    #pragma unroll
    for (int rt=0; rt<4; rt++)
      acc[rt][ct] = __builtin_amdgcn_mfma_f32_16x16x32_f16(a, mk8(b1w[rt]), acc[rt][ct], 0,0,0);
  }

  uint32_t bw[4][8][2];

  // identity repack (HW-verified): lane (r,q) D-tile c values j=0..3 ARE the
  // K=16 B-frag elements (k = c*16 + q*4 + j) for chunk c.
  #define REPACK16(BL)                                                       \
    _Pragma("unroll")                                                        \
    for (int rt=0; rt<4; rt++){                                              \
      _Pragma("unroll")                                                      \
      for (int c=0; c<8; c++){                                               \
        float v0 = acc[rt][c][0] + BL[c*16 + q*4 + 0]; v0 = v0>0.f?v0:0.f;   \
        float v1 = acc[rt][c][1] + BL[c*16 + q*4 + 1]; v1 = v1>0.f?v1:0.f;   \
        float v2 = acc[rt][c][2] + BL[c*16 + q*4 + 2]; v2 = v2>0.f?v2:0.f;   \
        float v3 = acc[rt][c][3] + BL[c*16 + q*4 + 3]; v3 = v3>0.f?v3:0.f;   \
        bw[rt][c][0] = pkh(v0, v1);                                          \
        bw[rt][c][1] = pkh(v2, v3);                                          \
      }                                                                      \
    }

  #define HIDDEN16(WOFF)                                                     \
    _Pragma("unroll")                                                        \
    for (int rt=0; rt<4; rt++)                                               \
      _Pragma("unroll")                                                      \
      for (int ct=0; ct<8; ct++){ v4f z={0.f,0.f,0.f,0.f}; acc[rt][ct]=z; }  \
    _Pragma("unroll")                                                        \
    for (int c=0; c<8; c++){                                                 \
      _Pragma("unroll")                                                      \
      for (int ct=0; ct<8; ct++){                                            \
        v4h a = *(const v4h*)(sm + (WOFF) + (uint32_t)(ct*16+r)*256u         \
                              + (uint32_t)((c*32 + q*8) ^ (r<<3)));          \
        _Pragma("unroll")                                                    \
        for (int rt=0; rt<4; rt++)                                           \
          acc[rt][ct] = __builtin_amdgcn_mfma_f32_16x16x16f16(               \
              a, mk4(bw[rt][c][0], bw[rt][c][1]), acc[rt][ct], 0,0,0);       \
      }                                                                      \
    }

  REPACK16(bl)
  HIDDEN16(MW2)
  REPACK16((bl+128))
  HIDDEN16(MW3)
  REPACK16((bl+256))

  // ---- layer 4 (K=16 chunks; outs 0,1 valid; LDS w4 rows 2..15 zero) ----
  v4f a4[4];
  #pragma unroll
  for (int rt=0; rt<4; rt++){ v4f z={0.f,0.f,0.f,0.f}; a4[rt]=z; }
  #pragma unroll
  for (int c=0; c<8; c++){
    v4h a = *(const v4h*)(sm + MW4 + (uint32_t)r*256u
                          + (uint32_t)((c*32 + q*8) ^ (r<<3)));
    #pragma unroll
    for (int rt=0; rt<4; rt++)
      a4[rt] = __builtin_amdgcn_mfma_f32_16x16x16f16(
          a, mk4(bw[rt][c][0], bw[rt][c][1]), a4[rt], 0,0,0);
  }
  if (q == 0){
    float c0 = bl[384], c1 = bl[385];
    #pragma unroll
    for (int rt=0; rt<4; rt++){
      int R = R0 + rt*16 + r;
      if (R < N){
        float2 v; v.x = a4[rt][0] + c0; v.y = a4[rt][1] + c1;
        *(float2*)(out + (size_t)R*2) = v;
      }
    }
  }
  #undef REPACK16
  #undef HIDDEN16
}

// ============================ fused fallback (verified round 1) ============================
template<int K, int O, int RTT, bool RELU>
__device__ __forceinline__ void mlp_layer(char* sm, uint32_t w_off, const float* bias, int wrow0, int lane)
{
  const int r = lane & 15;
  const int q = lane >> 4;
  v4f acc[RTT][O/16];
  #pragma unroll
  for (int rt=0;rt<RTT;rt++)
    #pragma unroll
    for (int ct=0;ct<O/16;ct++){ v4f z = {0.f,0.f,0.f,0.f}; acc[rt][ct] = z; }

  #pragma unroll
  for (int ks=0; ks<K/32; ks++){
    uint32_t abyte = (uint32_t)(ks*64 + q*16);
    v8h a[RTT];
    #pragma unroll
    for (int rt=0;rt<RTT;rt++)
      a[rt] = *(const v8h*)(sm + H_OFF + swz256((uint32_t)(wrow0 + rt*16 + r), abyte));
    #pragma unroll
    for (int ct=0; ct<O/16; ct++){
      uint32_t wrow = (uint32_t)(ct*16 + r);
      v8h b;
      if (K == 32) b = *(const v8h*)(sm + w_off + swz64 (wrow, abyte));
      else         b = *(const v8h*)(sm + w_off + swz256(wrow, abyte));
      #pragma unroll
      for (int rt=0;rt<RTT;rt++)
        acc[rt][ct] = __builtin_amdgcn_mfma_f32_16x16x32_f16(a[rt], b, acc[rt][ct], 0,0,0);
    }
  }
  #pragma unroll
  for (int rt=0;rt<RTT;rt++){
    #pragma unroll
    for (int ct=0; ct<O/16; ct++){
      float bv = bias[ct*16 + r];
      #pragma unroll
      for (int j=0;j<4;j++){
        float v = acc[rt][ct][j] + bv;
        if (RELU) v = v > 0.f ? v : 0.f;
        uint32_t row = (uint32_t)(wrow0 + rt*16 + q*4 + j);
        *(_Float16*)(sm + H_OFF + swz256(row, (uint32_t)((ct*16 + r)*2))) = (_Float16)v;
      }
    }
  }
}

__device__ __forceinline__ void sh_to_lds(char* sm, const float* __restrict__ x, int grow, uint32_t row)
{
  float dx = 2.f*x[grow*6+3]-1.f, dy = 2.f*x[grow*6+4]-1.f, dz = 2.f*x[grow*6+5]-1.f;
  float s[16]; sh16(dx,dy,dz,s);
  #pragma unroll
  for (int j=0;j<8;j++)
    *(uint32_t*)(sm + H_OFF + swz256(row, (uint32_t)(32 + 4*j))) = pkh(s[2*j], s[2*j+1]);
}

__global__ __launch_bounds__(NTHR, 2)
void ngp_fused(const float* __restrict__ x,
               const float* __restrict__ table,
               const float* __restrict__ W1, const float* __restrict__ b1,
               const float* __restrict__ W2, const float* __restrict__ b2,
               const float* __restrict__ W3, const float* __restrict__ b3,
               const float* __restrict__ W4, const float* __restrict__ b4,
               float* __restrict__ out, int N)
{
  extern __shared__ char sm[];
  const int tid  = (int)threadIdx.x;
  const int lane = tid & 63;
  const int wave = tid >> 6;

  for (int i = tid; i < 128*32; i += NTHR){
    uint32_t o = (uint32_t)(i >> 5), k = (uint32_t)(i & 31);
    *(_Float16*)(sm + W1_OFF + swz64(o, k*2u)) = (_Float16)W1[i];
  }
  for (int i = tid; i < 128*128; i += NTHR){
    uint32_t o = (uint32_t)(i >> 7), k = (uint32_t)(i & 127);
    *(_Float16*)(sm + W2_OFF + swz256(o, k*2u)) = (_Float16)W2[i];
    *(_Float16*)(sm + W3_OFF + swz256(o, k*2u)) = (_Float16)W3[i];
  }
  for (int i = tid; i < 2*128; i += NTHR){
    uint32_t o = (uint32_t)(i >> 7), k = (uint32_t)(i & 127);
    *(_Float16*)(sm + W4_OFF + swz256(o, k*2u)) = (_Float16)W4[i];
  }
  {
    float* bl = (float*)(sm + B_OFF);
    for (int i = tid; i < 128; i += NTHR){ bl[i] = b1[i]; bl[128+i] = b2[i]; bl[256+i] = b3[i]; }
    if (tid < 2) bl[384+tid] = b4[tid];
  }

  const int ntiles = (N + BM - 1) / BM;
  for (int tile = (int)blockIdx.x; tile < ntiles; tile += (int)gridDim.x){
    const int r0 = tile * BM;
    __syncthreads();

    #pragma unroll
    for (int t=0;t<4;t++){
      int task = t*NTHR + tid;
      int row  = task >> 3;
      int lev  = task & 7;
      int grow = r0 + row;
      if (grow < N){
        const float2* tbl = (const float2*)table + (size_t)lev*TSIZE;
        const uint32_t m = TSIZE-1u;
        float res = (float)(16 << lev);
        float px = x[grow*6+0]*res, py = x[grow*6+1]*res, pz = x[grow*6+2]*res;
        float fx = floorf(px), fy = floorf(py), fz = floorf(pz);
        float rx = px-fx, ry = py-fy, rz = pz-fz;
        uint32_t ix=(uint32_t)fx, iy=(uint32_t)fy, iz=(uint32_t)fz;
        uint32_t hx0=ix,      hx1=ix+1u;
        uint32_t hy0=iy*P2c,  hy1=(iy+1u)*P2c;
        uint32_t hz0=iz*P3c,  hz1=(iz+1u)*P3c;
        float2 f0 = tbl[(hx0^hy0^hz0)&m];
        float2 f1 = tbl[(hx1^hy0^hz0)&m];
        float2 f2 = tbl[(hx0^hy1^hz0)&m];
        float2 f3 = tbl[(hx1^hy1^hz0)&m];
        float2 f4 = tbl[(hx0^hy0^hz1)&m];
        float2 f5 = tbl[(hx1^hy0^hz1)&m];
        float2 f6 = tbl[(hx0^hy1^hz1)&m];
        float2 f7 = tbl[(hx1^hy1^hz1)&m];
        float wx0=1.f-rx, wy0=1.f-ry, wz0=1.f-rz;
        float w0=wx0*wy0*wz0, w1=rx*wy0*wz0, w2=wx0*ry*wz0, w3=rx*ry*wz0;
        float w4=wx0*wy0*rz,  w5=rx*wy0*rz,  w6=wx0*ry*rz,  w7=rx*ry*rz;
        float s0 = f0.x*w0+f1.x*w1+f2.x*w2+f3.x*w3+f4.x*w4+f5.x*w5+f6.x*w6+f7.x*w7;
        float s1 = f0.y*w0+f1.y*w1+f2.y*w2+f3.y*w3+f4.y*w4+f5.y*w5+f6.y*w6+f7.y*w7;
        *(uint32_t*)(sm + H_OFF + swz256((uint32_t)row, (uint32_t)(lev*4))) = pkh(s0, s1);
      }
    }
    if (tid < BM){
      int row = tid, grow = r0 + row;
      if (grow < N) sh_to_lds(sm, x, grow, (uint32_t)row);
    }
    __syncthreads();

    const int wrow0 = wave * 32;
    const float* bl = (const float*)(sm + B_OFF);
    mlp_layer<32, 128, 2, true>(sm, W1_OFF, bl,       wrow0, lane);
    mlp_layer<128,128, 2, true>(sm, W2_OFF, bl + 128, wrow0, lane);
    mlp_layer<128,128, 2, true>(sm, W3_OFF, bl + 256, wrow0, lane);
    {
      const int r = lane & 15, q = lane >> 4;
      v4f acc0 = {0.f,0.f,0.f,0.f}, acc1 = {0.f,0.f,0.f,0.f};
      #pragma unroll
      for (int ks=0; ks<4; ks++){
        uint32_t abyte = (uint32_t)(ks*64 + q*16);
        v8h a0 = *(const v8h*)(sm + H_OFF + swz256((uint32_t)(wrow0 + r),      abyte));
        v8h a1 = *(const v8h*)(sm + H_OFF + swz256((uint32_t)(wrow0 + 16 + r), abyte));
        v8h b  = *(const v8h*)(sm + W4_OFF + swz256((uint32_t)r, abyte));
        acc0 = __builtin_amdgcn_mfma_f32_16x16x32_f16(a0, b, acc0, 0,0,0);
        acc1 = __builtin_amdgcn_mfma_f32_16x16x32_f16(a1, b, acc1, 0,0,0);
      }
      if (r < 2){
        float bv = bl[384 + r];
        #pragma unroll
        for (int j=0;j<4;j++){
          uint32_t row0 = (uint32_t)(wrow0 + q*4 + j);
          *(float*)(sm + H_OFF + swz256(row0,       (uint32_t)(r*4))) = acc0[j] + bv;
          *(float*)(sm + H_OFF + swz256(row0 + 16u, (uint32_t)(r*4))) = acc1[j] + bv;
        }
      }
    }
    __syncthreads();

    {
      int row = tid >> 1, col = tid & 1;
      int grow = r0 + row;
      if (grow < N){
        out[grow*2 + col] = *(const float*)(sm + H_OFF + swz256((uint32_t)row, (uint32_t)(col*4)));
      }
    }
  }
}

extern "C" void kernel_launch(void* const* d_in, const int* in_sizes, int n_in,
                              void* d_out, int out_size, void* d_ws, size_t ws_size,
                              hipStream_t stream)
{
  const float* x  = (const float*)d_in[0];
  const float* tb = (const float*)d_in[1];
  const float* W1 = (const float*)d_in[2];
  const float* b1 = (const float*)d_in[3];
  const float* W2 = (const float*)d_in[4];
  const float* b2 = (const float*)d_in[5];
  const float* W3 = (const float*)d_in[6];
  const float* b3 = (const float*)d_in[7];
  const float* W4 = (const float*)d_in[8];
  const float* b4 = (const float*)d_in[9];
  float* out = (float*)d_out;
  const int N = in_sizes[0] / 6;

  const size_t tbl16_bytes  = (size_t)8 * TSIZE * 2 * sizeof(_Float16);   // 16 MB
  const size_t planes_bytes = (size_t)8 * (size_t)N * 4u;                 // 32 MB
  const size_t xyz_bytes    = (size_t)N * 16u;                            // 16 MB
  const size_t need_mid  = tbl16_bytes + planes_bytes + WIMG_BYTES;
  const size_t need_full = need_mid + xyz_bytes;

  if (ws_size >= need_mid){
    char* p = (char*)d_ws;
    _Float16* tbl16 = (_Float16*)p;                  p += tbl16_bytes;
    uint32_t* planes = (uint32_t*)p;                 p += planes_bytes;
    char*     wimg  = p;                             p += WIMG_BYTES;
    float4*   xyz   = (float4*)p;

    (void)hipFuncSetAttribute((const void*)mlp_oneshot4,
                              hipFuncAttributeMaxDynamicSharedMemorySize, (int)MLP_LDS_BYTES);

    const int n4 = (int)(8u*TSIZE*2u/4u);
    if (ws_size >= need_full){
      prep_all<<<2048, 256, 0, stream>>>(tb, tbl16, n4, x, xyz, N,
                                         W1, W2, W3, W4, b1, b2, b3, b4, wimg);
      encode4<<<4096, 512, 0, stream>>>(xyz, tbl16, planes, N);
    } else {
      prep_all<<<2048, 256, 0, stream>>>(tb, tbl16, n4, x, (float4*)nullptr, N,
                                         W1, W2, W3, W4, b1, b2, b3, b4, wimg);
      encode<<<4096, 256, 0, stream>>>(x, tbl16, planes, N);
    }

    const int nblk = (N + 511) / 512;   // one 512-row tile per block (8 waves x 64 rows)
    mlp_oneshot4<<<nblk, 512, MLP_LDS_BYTES, stream>>>(x, planes, (const float4*)wimg, out, N);
  } else {
    (void)hipFuncSetAttribute((const void*)ngp_fused,
                              hipFuncAttributeMaxDynamicSharedMemorySize, (int)LDS_BYTES);
    const int ntiles = (N + BM - 1) / BM;
    const int grid = ntiles < 1024 ? ntiles : 1024;
    ngp_fused<<<grid, NTHR, LDS_BYTES, stream>>>(x, tb, W1, b1, W2, b2, W3, b3, W4, b4, out, N);
  }
}

// Round 15
// 275.755 us; speedup vs baseline: 1.0854x; 1.0854x over previous
//
#include <hip/hip_runtime.h>
#include <stdint.h>

#define TSIZE   (1u<<19)
#define P2c 2654435761u
#define P3c 805459861u

#define NTHR 512          // fused fallback block
#define BM 256

// LDS layout (bytes) — fused fallback
#define H_OFF   0u
#define W1_OFF  65536u
#define W2_OFF  73728u
#define W3_OFF  106496u
#define W4_OFF  139264u
#define B_OFF   143360u
#define LDS_BYTES 144960u

// LDS layout (bytes) — mlp kernel (weights only, swizzled; VERIFIED R6-R13)
#define MW1   0u          // 128 rows x 64B   (8 KB)
#define MW2   8192u       // 128 rows x 256B  (32 KB)
#define MW3   40960u      // 128 rows x 256B  (32 KB)
#define MW4   73728u      // 16 rows x 256B   (4 KB)
#define MBIAS 77824u      // f32: b1[128] b2[128] b3[128] b4[2]
#define MLP_LDS_BYTES 79872u
#define WIMG_BYTES 81920u  // image padded to 16B multiple

typedef _Float16 v8h __attribute__((ext_vector_type(8)));
typedef _Float16 v4h __attribute__((ext_vector_type(4)));
typedef float    v4f __attribute__((ext_vector_type(4)));

__device__ __forceinline__ uint32_t swz256(uint32_t row, uint32_t off){ return row*256u + (off ^ ((row&7u)<<4)); }
__device__ __forceinline__ uint32_t swz64 (uint32_t row, uint32_t off){ return row*64u  + (off ^ ((row&3u)<<4)); }

__device__ __forceinline__ uint32_t pkh(float a, float b){
  union { _Float16 h[2]; uint32_t u; } t;
  t.h[0] = (_Float16)a; t.h[1] = (_Float16)b; return t.u;
}
__device__ __forceinline__ v8h mk8(const uint32_t* w){
  union { uint32_t u[4]; v8h h; } t;
  t.u[0]=w[0]; t.u[1]=w[1]; t.u[2]=w[2]; t.u[3]=w[3]; return t.h;
}
__device__ __forceinline__ v4h mk4(uint32_t a, uint32_t b){
  union { uint32_t u[2]; v4h h; } t;
  t.u[0]=a; t.u[1]=b; return t.h;
}

__device__ __forceinline__ void sh16(float dx, float dy, float dz, float* s){
  float x2=dx*dx, y2=dy*dy, z2=dz*dz;
  float xy=dx*dy, yz=dy*dz, xz=dx*dz;
  s[0]=0.28209479177387814f;
  s[1]=-0.48860251190291987f*dy;
  s[2]= 0.48860251190291987f*dz;
  s[3]=-0.48860251190291987f*dx;
  s[4]= 1.0925484305920792f*xy;
  s[5]=-1.0925484305920792f*yz;
  s[6]= 0.94617469575756f*z2-0.31539156525252f;
  s[7]=-1.0925484305920792f*xz;
  s[8]= 0.5462742152960396f*(x2-y2);
  s[9]= 0.5900435899266435f*dy*(-3.f*x2+y2);
  s[10]=2.890611442640554f*xy*dz;
  s[11]=0.4570457994644657f*dy*(1.f-5.f*z2);
  s[12]=0.3731763325901154f*dz*(5.f*z2-3.f);
  s[13]=0.4570457994644657f*dx*(1.f-5.f*z2);
  s[14]=1.445305721320277f*dz*(x2-y2);
  s[15]=0.5900435899266435f*dx*(-x2+3.f*y2);
}

// ============================ kernel 0: combined prep (table+wimg+xyz; R12-verified) ==
__global__ __launch_bounds__(256)
void prep_all(const float* __restrict__ t, _Float16* __restrict__ o, int n4,
              const float* __restrict__ x, float4* __restrict__ xyz, int N,
              const float* __restrict__ W1, const float* __restrict__ W2,
              const float* __restrict__ W3, const float* __restrict__ W4,
              const float* __restrict__ b1, const float* __restrict__ b2,
              const float* __restrict__ b3, const float* __restrict__ b4,
              char* __restrict__ img)
{
  int gid = (int)(blockIdx.x*256 + threadIdx.x);
  int stride = (int)(gridDim.x*256);
  for (int i = gid; i < n4; i += stride){
    float4 v = ((const float4*)t)[i];
    v4h h; h[0]=(_Float16)v.x; h[1]=(_Float16)v.y; h[2]=(_Float16)v.z; h[3]=(_Float16)v.w;
    ((v4h*)o)[i] = h;
    if (xyz && i < N){
      float4 p; p.x = x[i*6+0]; p.y = x[i*6+1]; p.z = x[i*6+2]; p.w = 0.f;
      xyz[i] = p;
    }
    if (i < 128*128){
      int row = i >> 7, k = i & 127;
      uint32_t byte = (uint32_t)(k*2) ^ (uint32_t)((row&15)<<3);
      *(_Float16*)(img + MW2 + (uint32_t)row*256u + byte) = (_Float16)W2[i];
      *(_Float16*)(img + MW3 + (uint32_t)row*256u + byte) = (_Float16)W3[i];
    }
    if (i < 128*32){
      int row = i >> 5, k = i & 31;
      uint32_t byte = (uint32_t)(k*2) ^ (uint32_t)((row&3)<<4);
      *(_Float16*)(img + MW1 + (uint32_t)row*64u + byte) = (_Float16)W1[i];
    }
    if (i < 16*128){
      int row = i >> 7, k = i & 127;
      uint32_t byte = (uint32_t)(k*2) ^ (uint32_t)((row&15)<<3);
      _Float16 v2 = (i < 256) ? (_Float16)W4[i] : (_Float16)0.f;
      *(_Float16*)(img + MW4 + (uint32_t)row*256u + byte) = v2;
    }
    if (i < 128){
      float* bl = (float*)(img + MBIAS);
      bl[i] = b1[i]; bl[128+i] = b2[i]; bl[256+i] = b3[i];
      if (i < 2) bl[384+i] = b4[i];
    }
  }
}

// ============================ encode compute (weights+interp from loaded corners) =====
__device__ __forceinline__ uint32_t enc_fin(float px, float py, float pz,
                                            uint32_t u0, uint32_t u1, uint32_t u2, uint32_t u3,
                                            uint32_t u4, uint32_t u5, uint32_t u6, uint32_t u7)
{
  float rx = px-floorf(px), ry = py-floorf(py), rz = pz-floorf(pz);
  float wx0=1.f-rx, wy0=1.f-ry, wz0=1.f-rz;
  float w0=wx0*wy0*wz0, w1=rx*wy0*wz0, w2=wx0*ry*wz0, w3=rx*ry*wz0;
  float w4=wx0*wy0*rz,  w5=rx*wy0*rz,  w6=wx0*ry*rz,  w7=rx*ry*rz;
  union { uint32_t u; _Float16 h[2]; } c0,c1,c2,c3,c4,c5,c6,c7;
  c0.u=u0; c1.u=u1; c2.u=u2; c3.u=u3; c4.u=u4; c5.u=u5; c6.u=u6; c7.u=u7;
  float s0 = (float)c0.h[0]*w0+(float)c1.h[0]*w1+(float)c2.h[0]*w2+(float)c3.h[0]*w3
           + (float)c4.h[0]*w4+(float)c5.h[0]*w5+(float)c6.h[0]*w6+(float)c7.h[0]*w7;
  float s1 = (float)c0.h[1]*w0+(float)c1.h[1]*w1+(float)c2.h[1]*w2+(float)c3.h[1]*w3
           + (float)c4.h[1]*w4+(float)c5.h[1]*w5+(float)c6.h[1]*w6+(float)c7.h[1]*w7;
  return pkh(s0, s1);
}

// ============================ kernel 1a: encode, 4 rows/thread, 2-phase ===============
// Phase 1 issues all 32 gathers (max memory-level parallelism), phase 2 interpolates.
__global__ __launch_bounds__(256)
void encode4(const float4* __restrict__ xyz, const _Float16* __restrict__ tb,
             uint32_t* __restrict__ planes, int N)
{
  const int lev = (int)(blockIdx.x & 7u);
  const int nch = (N + 1023) >> 10;                // chunks of 1024 rows
  const uint32_t* lvl = (const uint32_t*)(tb + (size_t)lev*TSIZE*2u);
  const float res = (float)(16 << lev);
  const uint32_t m = TSIZE-1u;
  uint32_t* plane = planes + (size_t)lev*(size_t)N;
  for (int c = (int)(blockIdx.x >> 3); c < nch; c += (int)(gridDim.x >> 3)){
    int row0 = c*1024 + (int)threadIdx.x;
    float px[4], py[4], pz[4];
    uint32_t g[4][8];
    bool ok[4];
    #pragma unroll
    for (int h=0; h<4; h++){
      int row = row0 + h*256;
      ok[h] = (row < N);
      int rc = ok[h] ? row : 0;
      float4 p = xyz[rc];
      px[h] = p.x*res; py[h] = p.y*res; pz[h] = p.z*res;
      uint32_t ix=(uint32_t)floorf(px[h]), iy=(uint32_t)floorf(py[h]), iz=(uint32_t)floorf(pz[h]);
      uint32_t hx0=ix,      hx1=ix+1u;
      uint32_t hy0=iy*P2c,  hy1=(iy+1u)*P2c;
      uint32_t hz0=iz*P3c,  hz1=(iz+1u)*P3c;
      g[h][0] = lvl[(hx0^hy0^hz0)&m];
      g[h][1] = lvl[(hx1^hy0^hz0)&m];
      g[h][2] = lvl[(hx0^hy1^hz0)&m];
      g[h][3] = lvl[(hx1^hy1^hz0)&m];
      g[h][4] = lvl[(hx0^hy0^hz1)&m];
      g[h][5] = lvl[(hx1^hy0^hz1)&m];
      g[h][6] = lvl[(hx0^hy1^hz1)&m];
      g[h][7] = lvl[(hx1^hy1^hz1)&m];
    }
    #pragma unroll
    for (int h=0; h<4; h++){
      if (ok[h]){
        plane[row0 + h*256] = enc_fin(px[h], py[h], pz[h],
                                      g[h][0],g[h][1],g[h][2],g[h][3],
                                      g[h][4],g[h][5],g[h][6],g[h][7]);
      }
    }
  }
}

// ============================ kernel 1b: encode from raw x (mid tier; R10-verified) ===
__global__ __launch_bounds__(256)
void encode(const float* __restrict__ x, const _Float16* __restrict__ tb,
            uint32_t* __restrict__ planes, int N)
{
  const int lev = (int)(blockIdx.x & 7u);
  const int nch = (N + 511) >> 9;
  const uint32_t* lvl = (const uint32_t*)(tb + (size_t)lev*TSIZE*2u);
  const float res = (float)(16 << lev);
  const uint32_t m = TSIZE-1u;
  uint32_t* plane = planes + (size_t)lev*(size_t)N;
  for (int c = (int)(blockIdx.x >> 3); c < nch; c += (int)(gridDim.x >> 3)){
    int row0 = c*512 + (int)threadIdx.x;
    #pragma unroll
    for (int h=0; h<2; h++){
      int row = row0 + h*256;
      if (row < N){
        float px = x[row*6+0]*res, py = x[row*6+1]*res, pz = x[row*6+2]*res;
        uint32_t ix=(uint32_t)floorf(px), iy=(uint32_t)floorf(py), iz=(uint32_t)floorf(pz);
        uint32_t hx0=ix,      hx1=ix+1u;
        uint32_t hy0=iy*P2c,  hy1=(iy+1u)*P2c;
        uint32_t hz0=iz*P3c,  hz1=(iz+1u)*P3c;
        plane[row] = enc_fin(px, py, pz,
                             lvl[(hx0^hy0^hz0)&m], lvl[(hx1^hy0^hz0)&m],
                             lvl[(hx0^hy1^hz0)&m], lvl[(hx1^hy1^hz0)&m],
                             lvl[(hx0^hy0^hz1)&m], lvl[(hx1^hy0^hz1)&m],
                             lvl[(hx0^hy1^hz1)&m], lvl[(hx1^hy1^hz1)&m]);
      }
    }
  }
}

// ============================ kernel 2: MLP — one-shot, image-staged (R11/R12-verified)
__global__ __launch_bounds__(512, 1)
void mlp_oneshot(const float* __restrict__ x, const uint32_t* __restrict__ planes,
                 const float4* __restrict__ wimg,
                 float* __restrict__ out, int N)
{
  extern __shared__ char sm[];
  const int tid  = (int)threadIdx.x;
  const int lane = tid & 63;
  const int wave = tid >> 6;      // 0..7
  const int r = lane & 15;
  const int q = lane >> 4;

  // ---- stage weight image: linear, coalesced, conflict-free ----
  {
    float4* l = (float4*)sm;
    for (int j = tid; j < (int)(MLP_LDS_BYTES/16); j += 512) l[j] = wimg[j];
  }
  __syncthreads();
  const float* bl = (const float*)(sm + MBIAS);

  const int R0 = (int)blockIdx.x*256 + wave*32;

  // ---- layer-1 B-frags from encoded features (K=32, k-chunk = q*8..q*8+7) ----
  uint32_t b1w[2][4];
  #pragma unroll
  for (int rt=0; rt<2; rt++){
    int R  = R0 + rt*16 + r;
    int Rc = (R < N) ? R : 0;
    if (q < 2){
      #pragma unroll
      for (int i=0; i<4; i++)
        b1w[rt][i] = planes[(size_t)(q*4+i)*(size_t)N + (size_t)Rc];
    } else {
      float dx = 2.f*x[Rc*6+3]-1.f, dy = 2.f*x[Rc*6+4]-1.f, dz = 2.f*x[Rc*6+5]-1.f;
      float s[16]; sh16(dx, dy, dz, s);
      if (q == 2){
        b1w[rt][0]=pkh(s[0],s[1]);  b1w[rt][1]=pkh(s[2],s[3]);
        b1w[rt][2]=pkh(s[4],s[5]);  b1w[rt][3]=pkh(s[6],s[7]);
      } else {
        b1w[rt][0]=pkh(s[8],s[9]);   b1w[rt][1]=pkh(s[10],s[11]);
        b1w[rt][2]=pkh(s[12],s[13]); b1w[rt][3]=pkh(s[14],s[15]);
      }
    }
  }

  v4f acc[2][8];
  #pragma unroll
  for (int rt=0; rt<2; rt++)
    #pragma unroll
    for (int ct=0; ct<8; ct++){ v4f z={0.f,0.f,0.f,0.f}; acc[rt][ct]=z; }

  // ---- layer 1 (K=32 MFMA, A from LDS w1; R6-verified address) ----
  #pragma unroll
  for (int ct=0; ct<8; ct++){
    v8h a = *(const v8h*)(sm + MW1 + (uint32_t)(ct*16+r)*64u
                          + (uint32_t)((q*16) ^ ((r&3)<<4)));
    #pragma unroll
    for (int rt=0; rt<2; rt++)
      acc[rt][ct] = __builtin_amdgcn_mfma_f32_16x16x32_f16(a, mk8(b1w[rt]), acc[rt][ct], 0,0,0);
  }

  uint32_t bw[2][8][2];

  // identity repack (HW-verified): lane (r,q) D-tile c values j=0..3 ARE the
  // K=16 B-frag elements (k = c*16 + q*4 + j) for chunk c.
  #define REPACK16(BL)                                                       \
    _Pragma("unroll")                                                        \
    for (int rt=0; rt<2; rt++){                                              \
      _Pragma("unroll")                                                      \
      for (int c=0; c<8; c++){                                               \
        float v0 = acc[rt][c][0] + BL[c*16 + q*4 + 0]; v0 = v0>0.f?v0:0.f;   \
        float v1 = acc[rt][c][1] + BL[c*16 + q*4 + 1]; v1 = v1>0.f?v1:0.f;   \
        float v2 = acc[rt][c][2] + BL[c*16 + q*4 + 2]; v2 = v2>0.f?v2:0.f;   \
        float v3 = acc[rt][c][3] + BL[c*16 + q*4 + 3]; v3 = v3>0.f?v3:0.f;   \
        bw[rt][c][0] = pkh(v0, v1);                                          \
        bw[rt][c][1] = pkh(v2, v3);                                          \
      }                                                                      \
    }

  #define HIDDEN16(WOFF)                                                     \
    _Pragma("unroll")                                                        \
    for (int rt=0; rt<2; rt++)                                               \
      _Pragma("unroll")                                                      \
      for (int ct=0; ct<8; ct++){ v4f z={0.f,0.f,0.f,0.f}; acc[rt][ct]=z; }  \
    _Pragma("unroll")                                                        \
    for (int c=0; c<8; c++){                                                 \
      _Pragma("unroll")                                                      \
      for (int ct=0; ct<8; ct++){                                            \
        v4h a = *(const v4h*)(sm + (WOFF) + (uint32_t)(ct*16+r)*256u         \
                              + (uint32_t)((c*32 + q*8) ^ (r<<3)));          \
        _Pragma("unroll")                                                    \
        for (int rt=0; rt<2; rt++)                                           \
          acc[rt][ct] = __builtin_amdgcn_mfma_f32_16x16x16f16(               \
              a, mk4(bw[rt][c][0], bw[rt][c][1]), acc[rt][ct], 0,0,0);       \
      }                                                                      \
    }

  REPACK16(bl)
  HIDDEN16(MW2)
  REPACK16((bl+128))
  HIDDEN16(MW3)
  REPACK16((bl+256))

  // ---- layer 4 (K=16 chunks; outs 0,1 valid; LDS w4 rows 2..15 zero) ----
  v4f a4[2];
  #pragma unroll
  for (int rt=0; rt<2; rt++){ v4f z={0.f,0.f,0.f,0.f}; a4[rt]=z; }
  #pragma unroll
  for (int c=0; c<8; c++){
    v4h a = *(const v4h*)(sm + MW4 + (uint32_t)r*256u
                          + (uint32_t)((c*32 + q*8) ^ (r<<3)));
    #pragma unroll
    for (int rt=0; rt<2; rt++)
      a4[rt] = __builtin_amdgcn_mfma_f32_16x16x16f16(
          a, mk4(bw[rt][c][0], bw[rt][c][1]), a4[rt], 0,0,0);
  }
  if (q == 0){
    float c0 = bl[384], c1 = bl[385];
    #pragma unroll
    for (int rt=0; rt<2; rt++){
      int R = R0 + rt*16 + r;
      if (R < N){
        float2 v; v.x = a4[rt][0] + c0; v.y = a4[rt][1] + c1;
        *(float2*)(out + (size_t)R*2) = v;
      }
    }
  }
  #undef REPACK16
  #undef HIDDEN16
}

// ============================ fused fallback (verified round 1) ============================
template<int K, int O, int RTT, bool RELU>
__device__ __forceinline__ void mlp_layer(char* sm, uint32_t w_off, const float* bias, int wrow0, int lane)
{
  const int r = lane & 15;
  const int q = lane >> 4;
  v4f acc[RTT][O/16];
  #pragma unroll
  for (int rt=0;rt<RTT;rt++)
    #pragma unroll
    for (int ct=0;ct<O/16;ct++){ v4f z = {0.f,0.f,0.f,0.f}; acc[rt][ct] = z; }

  #pragma unroll
  for (int ks=0; ks<K/32; ks++){
    uint32_t abyte = (uint32_t)(ks*64 + q*16);
    v8h a[RTT];
    #pragma unroll
    for (int rt=0;rt<RTT;rt++)
      a[rt] = *(const v8h*)(sm + H_OFF + swz256((uint32_t)(wrow0 + rt*16 + r), abyte));
    #pragma unroll
    for (int ct=0; ct<O/16; ct++){
      uint32_t wrow = (uint32_t)(ct*16 + r);
      v8h b;
      if (K == 32) b = *(const v8h*)(sm + w_off + swz64 (wrow, abyte));
      else         b = *(const v8h*)(sm + w_off + swz256(wrow, abyte));
      #pragma unroll
      for (int rt=0;rt<RTT;rt++)
        acc[rt][ct] = __builtin_amdgcn_mfma_f32_16x16x32_f16(a[rt], b, acc[rt][ct], 0,0,0);
    }
  }
  #pragma unroll
  for (int rt=0;rt<RTT;rt++){
    #pragma unroll
    for (int ct=0; ct<O/16; ct++){
      float bv = bias[ct*16 + r];
      #pragma unroll
      for (int j=0;j<4;j++){
        float v = acc[rt][ct][j] + bv;
        if (RELU) v = v > 0.f ? v : 0.f;
        uint32_t row = (uint32_t)(wrow0 + rt*16 + q*4 + j);
        *(_Float16*)(sm + H_OFF + swz256(row, (uint32_t)((ct*16 + r)*2))) = (_Float16)v;
      }
    }
  }
}

__device__ __forceinline__ void sh_to_lds(char* sm, const float* __restrict__ x, int grow, uint32_t row)
{
  float dx = 2.f*x[grow*6+3]-1.f, dy = 2.f*x[grow*6+4]-1.f, dz = 2.f*x[grow*6+5]-1.f;
  float s[16]; sh16(dx,dy,dz,s);
  #pragma unroll
  for (int j=0;j<8;j++)
    *(uint32_t*)(sm + H_OFF + swz256(row, (uint32_t)(32 + 4*j))) = pkh(s[2*j], s[2*j+1]);
}

__global__ __launch_bounds__(NTHR, 2)
void ngp_fused(const float* __restrict__ x,
               const float* __restrict__ table,
               const float* __restrict__ W1, const float* __restrict__ b1,
               const float* __restrict__ W2, const float* __restrict__ b2,
               const float* __restrict__ W3, const float* __restrict__ b3,
               const float* __restrict__ W4, const float* __restrict__ b4,
               float* __restrict__ out, int N)
{
  extern __shared__ char sm[];
  const int tid  = (int)threadIdx.x;
  const int lane = tid & 63;
  const int wave = tid >> 6;

  for (int i = tid; i < 128*32; i += NTHR){
    uint32_t o = (uint32_t)(i >> 5), k = (uint32_t)(i & 31);
    *(_Float16*)(sm + W1_OFF + swz64(o, k*2u)) = (_Float16)W1[i];
  }
  for (int i = tid; i < 128*128; i += NTHR){
    uint32_t o = (uint32_t)(i >> 7), k = (uint32_t)(i & 127);
    *(_Float16*)(sm + W2_OFF + swz256(o, k*2u)) = (_Float16)W2[i];
    *(_Float16*)(sm + W3_OFF + swz256(o, k*2u)) = (_Float16)W3[i];
  }
  for (int i = tid; i < 2*128; i += NTHR){
    uint32_t o = (uint32_t)(i >> 7), k = (uint32_t)(i & 127);
    *(_Float16*)(sm + W4_OFF + swz256(o, k*2u)) = (_Float16)W4[i];
  }
  {
    float* bl = (float*)(sm + B_OFF);
    for (int i = tid; i < 128; i += NTHR){ bl[i] = b1[i]; bl[128+i] = b2[i]; bl[256+i] = b3[i]; }
    if (tid < 2) bl[384+tid] = b4[tid];
  }

  const int ntiles = (N + BM - 1) / BM;
  for (int tile = (int)blockIdx.x; tile < ntiles; tile += (int)gridDim.x){
    const int r0 = tile * BM;
    __syncthreads();

    #pragma unroll
    for (int t=0;t<4;t++){
      int task = t*NTHR + tid;
      int row  = task >> 3;
      int lev  = task & 7;
      int grow = r0 + row;
      if (grow < N){
        const float2* tbl = (const float2*)table + (size_t)lev*TSIZE;
        const uint32_t m = TSIZE-1u;
        float res = (float)(16 << lev);
        float px = x[grow*6+0]*res, py = x[grow*6+1]*res, pz = x[grow*6+2]*res;
        float fx = floorf(px), fy = floorf(py), fz = floorf(pz);
        float rx = px-fx, ry = py-fy, rz = pz-fz;
        uint32_t ix=(uint32_t)fx, iy=(uint32_t)fy, iz=(uint32_t)fz;
        uint32_t hx0=ix,      hx1=ix+1u;
        uint32_t hy0=iy*P2c,  hy1=(iy+1u)*P2c;
        uint32_t hz0=iz*P3c,  hz1=(iz+1u)*P3c;
        float2 f0 = tbl[(hx0^hy0^hz0)&m];
        float2 f1 = tbl[(hx1^hy0^hz0)&m];
        float2 f2 = tbl[(hx0^hy1^hz0)&m];
        float2 f3 = tbl[(hx1^hy1^hz0)&m];
        float2 f4 = tbl[(hx0^hy0^hz1)&m];
        float2 f5 = tbl[(hx1^hy0^hz1)&m];
        float2 f6 = tbl[(hx0^hy1^hz1)&m];
        float2 f7 = tbl[(hx1^hy1^hz1)&m];
        float wx0=1.f-rx, wy0=1.f-ry, wz0=1.f-rz;
        float w0=wx0*wy0*wz0, w1=rx*wy0*wz0, w2=wx0*ry*wz0, w3=rx*ry*wz0;
        float w4=wx0*wy0*rz,  w5=rx*wy0*rz,  w6=wx0*ry*rz,  w7=rx*ry*rz;
        float s0 = f0.x*w0+f1.x*w1+f2.x*w2+f3.x*w3+f4.x*w4+f5.x*w5+f6.x*w6+f7.x*w7;
        float s1 = f0.y*w0+f1.y*w1+f2.y*w2+f3.y*w3+f4.y*w4+f5.y*w5+f6.y*w6+f7.y*w7;
        *(uint32_t*)(sm + H_OFF + swz256((uint32_t)row, (uint32_t)(lev*4))) = pkh(s0, s1);
      }
    }
    if (tid < BM){
      int row = tid, grow = r0 + row;
      if (grow < N) sh_to_lds(sm, x, grow, (uint32_t)row);
    }
    __syncthreads();

    const int wrow0 = wave * 32;
    const float* bl = (const float*)(sm + B_OFF);
    mlp_layer<32, 128, 2, true>(sm, W1_OFF, bl,       wrow0, lane);
    mlp_layer<128,128, 2, true>(sm, W2_OFF, bl + 128, wrow0, lane);
    mlp_layer<128,128, 2, true>(sm, W3_OFF, bl + 256, wrow0, lane);
    {
      const int r = lane & 15, q = lane >> 4;
      v4f acc0 = {0.f,0.f,0.f,0.f}, acc1 = {0.f,0.f,0.f,0.f};
      #pragma unroll
      for (int ks=0; ks<4; ks++){
        uint32_t abyte = (uint32_t)(ks*64 + q*16);
        v8h a0 = *(const v8h*)(sm + H_OFF + swz256((uint32_t)(wrow0 + r),      abyte));
        v8h a1 = *(const v8h*)(sm + H_OFF + swz256((uint32_t)(wrow0 + 16 + r), abyte));
        v8h b  = *(const v8h*)(sm + W4_OFF + swz256((uint32_t)r, abyte));
        acc0 = __builtin_amdgcn_mfma_f32_16x16x32_f16(a0, b, acc0, 0,0,0);
        acc1 = __builtin_amdgcn_mfma_f32_16x16x32_f16(a1, b, acc1, 0,0,0);
      }
      if (r < 2){
        float bv = bl[384 + r];
        #pragma unroll
        for (int j=0;j<4;j++){
          uint32_t row0 = (uint32_t)(wrow0 + q*4 + j);
          *(float*)(sm + H_OFF + swz256(row0,       (uint32_t)(r*4))) = acc0[j] + bv;
          *(float*)(sm + H_OFF + swz256(row0 + 16u, (uint32_t)(r*4))) = acc1[j] + bv;
        }
      }
    }
    __syncthreads();

    {
      int row = tid >> 1, col = tid & 1;
      int grow = r0 + row;
      if (grow < N){
        out[grow*2 + col] = *(const float*)(sm + H_OFF + swz256((uint32_t)row, (uint32_t)(col*4)));
      }
    }
  }
}

extern "C" void kernel_launch(void* const* d_in, const int* in_sizes, int n_in,
                              void* d_out, int out_size, void* d_ws, size_t ws_size,
                              hipStream_t stream)
{
  const float* x  = (const float*)d_in[0];
  const float* tb = (const float*)d_in[1];
  const float* W1 = (const float*)d_in[2];
  const float* b1 = (const float*)d_in[3];
  const float* W2 = (const float*)d_in[4];
  const float* b2 = (const float*)d_in[5];
  const float* W3 = (const float*)d_in[6];
  const float* b3 = (const float*)d_in[7];
  const float* W4 = (const float*)d_in[8];
  const float* b4 = (const float*)d_in[9];
  float* out = (float*)d_out;
  const int N = in_sizes[0] / 6;

  const size_t tbl16_bytes  = (size_t)8 * TSIZE * 2 * sizeof(_Float16);   // 16 MB
  const size_t planes_bytes = (size_t)8 * (size_t)N * 4u;                 // 32 MB
  const size_t xyz_bytes    = (size_t)N * 16u;                            // 16 MB
  const size_t need_mid  = tbl16_bytes + planes_bytes + WIMG_BYTES;
  const size_t need_full = need_mid + xyz_bytes;

  if (ws_size >= need_mid){
    char* p = (char*)d_ws;
    _Float16* tbl16 = (_Float16*)p;                  p += tbl16_bytes;
    uint32_t* planes = (uint32_t*)p;                 p += planes_bytes;
    char*     wimg  = p;                             p += WIMG_BYTES;
    float4*   xyz   = (float4*)p;

    (void)hipFuncSetAttribute((const void*)mlp_oneshot,
                              hipFuncAttributeMaxDynamicSharedMemorySize, (int)MLP_LDS_BYTES);

    const int n4 = (int)(8u*TSIZE*2u/4u);
    if (ws_size >= need_full){
      prep_all<<<2048, 256, 0, stream>>>(tb, tbl16, n4, x, xyz, N,
                                         W1, W2, W3, W4, b1, b2, b3, b4, wimg);
      encode4<<<4096, 256, 0, stream>>>(xyz, tbl16, planes, N);
    } else {
      prep_all<<<2048, 256, 0, stream>>>(tb, tbl16, n4, x, (float4*)nullptr, N,
                                         W1, W2, W3, W4, b1, b2, b3, b4, wimg);
      encode<<<4096, 256, 0, stream>>>(x, tbl16, planes, N);
    }

    const int ntiles = (N + 255) / 256;   // one 256-row tile per block
    mlp_oneshot<<<ntiles, 512, MLP_LDS_BYTES, stream>>>(x, planes, (const float4*)wimg, out, N);
  } else {
    (void)hipFuncSetAttribute((const void*)ngp_fused,
                              hipFuncAttributeMaxDynamicSharedMemorySize, (int)LDS_BYTES);
    const int ntiles = (N + BM - 1) / BM;
    const int grid = ntiles < 1024 ? ntiles : 1024;
    ngp_fused<<<grid, NTHR, LDS_BYTES, stream>>>(x, tb, W1, b1, W2, b2, W3, b3, W4, b4, out, N);
  }
}